// Round 13
// baseline (328.482 us; speedup 1.0000x reference)
//
#include <hip/hip_runtime.h>
#include <hip/hip_bf16.h>

// SelfAttention non-local block: B=8, C=512, N=4096, CQK=32.  All-MFMA bf16 path.
// v14 (resubmission — round-12 bench failed on container acquisition):
//  - pass2 runs ~926 TF = the 2-barrier-structure ceiling; occupancy is hard-capped
//    at 2 waves/SIMD (acc 128 AGPR + ~128 VGPR = 256/wave vs 512 pool). Remaining
//    lever: barrier amortization. Chunk=128m halves barrier events (64->32).
//  - PT[2][128n x 128m] = 64 KB (1 block/CU, fits). Produce 8 tiles/wave
//    (M = 2*Mw+j). Consume in 4 quarters of 32 m; va0/va1 ping-pong reloaded
//    mid-chunk; P-reads batched 4+4/quarter (pg[4]/rr[4], freeing 32 VGPR to
//    pay for aqp[2]/l4p[2] -> arch VGPR stays <=128, the 2-waves/SIMD guard).
//  - keeps raw lgkm-only chunk barrier + setprio(1) consume clusters.
// ws: vb 33.5MB | qb 2MB | kb 2MB | Wvb 512KB | Wqb 32KB | Wkb 32KB | Lneg 128KB

typedef __attribute__((ext_vector_type(8))) short s16x8;
typedef __attribute__((ext_vector_type(4))) float f32x4;

#define MFMA16(a, b, c) __builtin_amdgcn_mfma_f32_16x16x32_bf16((a), (b), (c), 0, 0, 0)

__device__ __forceinline__ ushort f2bf(float f) {
  union { float f; unsigned u; } v; v.f = f;
  return (ushort)((v.u + 0x8000u) >> 16);
}
__device__ __forceinline__ unsigned pack_bf16(float lo, float hi) {  // (hi<<16)|lo
  union { float f; unsigned u; } a, b; a.f = lo; b.f = hi;
  return __builtin_amdgcn_perm(b.u + 0x8000u, a.u + 0x8000u, 0x07060302u);
}
__device__ __forceinline__ float fexp2(float x) { return __builtin_amdgcn_exp2f(x); }

// Raw chunk barrier: publish DS writes, sync, but leave global loads in flight.
__device__ __forceinline__ void chunk_barrier() {
  asm volatile("s_waitcnt lgkmcnt(0)" ::: "memory");
  __builtin_amdgcn_s_barrier();
  __builtin_amdgcn_sched_barrier(0);
}

// ---------------- kernel 1: weights -> bf16 (Wq pre-scaled by log2e) ----------------
__global__ void k_cvt_w(const float* __restrict__ Wq, const float* __restrict__ Wk,
                        const float* __restrict__ Wv, ushort* __restrict__ Wqb,
                        ushort* __restrict__ Wkb, ushort* __restrict__ Wvb) {
  int i = blockIdx.x * 256 + threadIdx.x;
  if (i < 262144) Wvb[i] = f2bf(Wv[i]);
  else if (i < 278528) Wqb[i - 262144] = f2bf(Wq[i - 262144] * 1.4426950408889634f);
  else if (i < 294912) Wkb[i - 278528] = f2bf(Wk[i - 278528]);
}

// ---------------- kernel 2: fused transpose + q/k/v projection ----------------
__global__ __launch_bounds__(256, 2) void k_proj(const float* __restrict__ x,
                                                 const ushort* __restrict__ Wqb,
                                                 const ushort* __restrict__ Wkb,
                                                 const ushort* __restrict__ Wvb,
                                                 ushort* __restrict__ qb,
                                                 ushort* __restrict__ kb,
                                                 ushort* __restrict__ vb) {
  const int b = blockIdx.y, n0 = blockIdx.x * 64;
  const int t = threadIdx.x;
  const int lane = t & 63, w = t >> 6;
  const int quad = lane >> 4, l15 = lane & 15;

  __shared__ __align__(16) ushort XB[64 * 512];  // [n][c] bf16, granule-swizzled; 64 KB
  __shared__ uint U[2][2][32][17];               // [buf][pair-half][c-row][c4]; 8.5 KB

  const float* x_b = x + (size_t)b * 512 * 4096;

  auto ldX = [&](int s, float4& fa, float4& fb) {
    const int c0s = s * 32;
    const float* p = x_b + (size_t)(c0s + (t >> 4)) * 4096 + n0 + (t & 15) * 4;
    fa = *(const float4*)p;
    fb = *(const float4*)(p + (size_t)16 * 4096);
  };
  auto packU = [&](int ub, const float4& fa, const float4& fb) {
    const int cr = t >> 4, c4 = t & 15;
    U[ub][0][cr][c4] = pack_bf16(fa.x, fa.y);
    U[ub][1][cr][c4] = pack_bf16(fa.z, fa.w);
    U[ub][0][cr + 16][c4] = pack_bf16(fb.x, fb.y);
    U[ub][1][cr + 16][c4] = pack_bf16(fb.z, fb.w);
  };
  auto phase2 = [&](int ub, int s) {
    const int n = t & 63, gl = t >> 6;
    const int h = (n >> 1) & 1, c4 = n >> 2;
    const uint sel = (n & 1) ? 0x07060302u : 0x05040100u;
    uint o[4];
#pragma unroll
    for (int j = 0; j < 4; ++j) {
      uint ua = U[ub][h][gl * 8 + 2 * j][c4];
      uint ubv = U[ub][h][gl * 8 + 2 * j + 1][c4];
      o[j] = __builtin_amdgcn_perm(ubv, ua, sel);
    }
    const int gfull = s * 4 + gl;
    const int gsw = gfull ^ (n & 7);
    *(uint4*)((char*)XB + n * 1024 + gsw * 16) = *(uint4*)o;
  };

  float4 fa0, fb0, fa1, fb1;
  ldX(0, fa0, fb0);
  packU(0, fa0, fb0);
  ldX(1, fa1, fb1);
  __syncthreads();
#pragma unroll
  for (int s = 0; s < 16; s += 2) {
    phase2(0, s);
    if (s < 14) ldX(s + 2, fa0, fb0);
    packU(1, fa1, fb1);
    __syncthreads();
    phase2(1, s + 1);
    if (s < 14) {
      packU(0, fa0, fb0);
      ldX(s + 3, fa1, fb1);
    }
    __syncthreads();
  }

  const ushort* Wqk = (w < 2) ? (Wqb + (size_t)(w * 16 + l15) * 512)
                              : (Wkb + (size_t)((w - 2) * 16 + l15) * 512);

  f32x4 accv[8][4], accqk[4];
#pragma unroll
  for (int i = 0; i < 8; ++i)
#pragma unroll
    for (int nt = 0; nt < 4; ++nt) accv[i][nt] = {0.f, 0.f, 0.f, 0.f};
#pragma unroll
  for (int nt = 0; nt < 4; ++nt) accqk[nt] = {0.f, 0.f, 0.f, 0.f};

  const char* XBb = (const char*)XB;
  for (int k0 = 0; k0 < 512; k0 += 32) {
    s16x8 bx[4];
#pragma unroll
    for (int nt = 0; nt < 4; ++nt) {
      const int nl = nt * 16 + l15;
      bx[nt] = *(const s16x8*)(XBb + nl * 1024 + ((((k0 >> 3) + quad) ^ (nl & 7)) << 4));
    }
#pragma unroll
    for (int i = 0; i < 8; ++i) {
      s16x8 av = *(const s16x8*)(Wvb + (size_t)((8 * w + i) * 16 + l15) * 512 + k0 + quad * 8);
#pragma unroll
      for (int nt = 0; nt < 4; ++nt) accv[i][nt] = MFMA16(bx[nt], av, accv[i][nt]);  // D[n][c]
    }
    s16x8 aqk = *(const s16x8*)(Wqk + k0 + quad * 8);
#pragma unroll
    for (int nt = 0; nt < 4; ++nt) accqk[nt] = MFMA16(aqk, bx[nt], accqk[nt]);
  }

  ushort* vb_b = vb + (size_t)b * 512 * 4096;
#pragma unroll
  for (int i = 0; i < 8; ++i)
#pragma unroll
    for (int nt = 0; nt < 4; ++nt) {
      ushort4 u;
      u.x = f2bf(accv[i][nt][0]); u.y = f2bf(accv[i][nt][1]);
      u.z = f2bf(accv[i][nt][2]); u.w = f2bf(accv[i][nt][3]);
      *(ushort4*)(vb_b + (size_t)((8 * w + i) * 16 + l15) * 4096 + n0 + nt * 16 + quad * 4) = u;
    }

  ushort* qk_out = (w < 2) ? (qb + (size_t)b * 4096 * 32) : (kb + (size_t)b * 4096 * 32);
#pragma unroll
  for (int nt = 0; nt < 4; ++nt) {
    ushort4 u;
    u.x = f2bf(accqk[nt][0]); u.y = f2bf(accqk[nt][1]);
    u.z = f2bf(accqk[nt][2]); u.w = f2bf(accqk[nt][3]);
    *(ushort4*)(qk_out + (size_t)(n0 + nt * 16 + l15) * 32 + (w & 1) * 16 + quad * 4) = u;
  }
}

// ---------------- kernel 3: pass1 — Lneg[b][m] = -log2(sum_n 2^(S'[m,n])) ----------------
__global__ __launch_bounds__(256) void k_pass1(const ushort* __restrict__ qb,
                                               const ushort* __restrict__ kb,
                                               float* __restrict__ Lneg) {
  const int b = blockIdx.y, mt = blockIdx.x;
  const int lane = threadIdx.x & 63, w = threadIdx.x >> 6;
  const int quad = lane >> 4, l15 = lane & 15;
  const int m = mt * 64 + w * 16;
  const ushort* qb_b = qb + (size_t)b * 4096 * 32;
  const ushort* kb_b = kb + (size_t)b * 4096 * 32;
  const s16x8 aqf = *(const s16x8*)(qb_b + (size_t)(m + l15) * 32 + quad * 8);
  float ps[4] = {0.f, 0.f, 0.f, 0.f};
  const f32x4 zf = {0.f, 0.f, 0.f, 0.f};
  for (int n0 = 0; n0 < 4096; n0 += 64) {
#pragma unroll
    for (int nt = 0; nt < 4; ++nt) {
      s16x8 bk = *(const s16x8*)(kb_b + (size_t)(n0 + nt * 16 + l15) * 32 + quad * 8);
      f32x4 s = MFMA16(aqf, bk, zf);
#pragma unroll
      for (int r = 0; r < 4; ++r) ps[r] += fexp2(s[r]);
    }
  }
  for (int off = 1; off < 16; off <<= 1)
#pragma unroll
    for (int r = 0; r < 4; ++r) ps[r] += __shfl_xor(ps[r], off, 64);
  if (l15 == 0)
#pragma unroll
    for (int r = 0; r < 4; ++r)
      Lneg[(size_t)b * 4096 + m + quad * 4 + r] = -log2f(ps[r]);
}

// ---------------- kernel 4: pass2 — out = V @ 2^(S' + Lneg) ----------------
// Grid 256 = 8 b (XCD-aligned: blk&7) x 32 ntb. Block 8 waves (512 thr): tile
// 512c x 128n, chunk 128 m (32 barriers). Per chunk: raw barrier (lgkm only) ->
// 4 P-reads -> produce x8 (reg-only inputs, chunk+1 into buf^1) -> loadQ ->
// 4 consume-quarters of 32 m (va0/va1 ping-pong, P-reads 4+4 interleaved,
// setprio(1) around MFMA clusters, V reloads between quarters).
__global__ __launch_bounds__(512, 2) void k_pass2(const ushort* __restrict__ qb,
                                                  const ushort* __restrict__ kb,
                                                  const ushort* __restrict__ vb,
                                                  const float* __restrict__ Lneg,
                                                  float* __restrict__ out) {
  const int blk = blockIdx.x;
  const int b = blk & 7, ntb = blk >> 3;
  const int nbase = ntb * 128;
  const int lane = threadIdx.x & 63, w = threadIdx.x >> 6;   // 8 waves
  const int quad = lane >> 4, l15 = lane & 15;
  const int cbase = w * 64;
  const int swz = l15 & 7;
  const int Mw = w >> 1;               // produce m-tile pair base: M in {2Mw, 2Mw+1}
  const int Tb = (w & 1) * 4;          // produce n-tile base (0 or 4)

  // [buf][n-row 0..127][m 0..127] bf16; row stride 256 B; 16B-granule XOR swizzle
  __shared__ __align__(16) ushort PT[2][128 * 128];  // 64 KB

  const ushort* qb_b = qb + (size_t)b * 4096 * 32;
  const ushort* kb_b = kb + (size_t)b * 4096 * 32;
  const ushort* vb_b = vb + (size_t)b * 512 * 4096;
  const float* L_b = Lneg + (size_t)b * 4096;

  s16x8 kf[4];  // K rows for this wave's 4 produce n-tiles
#pragma unroll
  for (int i = 0; i < 4; ++i)
    kf[i] = *(const s16x8*)(kb_b + (size_t)(nbase + (Tb + i) * 16 + l15) * 32 + quad * 8);

  f32x4 acc[4][8];
#pragma unroll
  for (int ci = 0; ci < 4; ++ci)
#pragma unroll
    for (int nt = 0; nt < 8; ++nt) acc[ci][nt] = {0.f, 0.f, 0.f, 0.f};

  s16x8 aqp[2];     // prefetched q A-frags for next produce (2 m-tiles)
  float4 l4p[2];    // prefetched Lneg
  s16x8 va0[4], va1[4];  // v A-frags: ping-pong over 32-m quarters

  auto loadQ = [&](int c2) {
    const int m0 = c2 * 128;
#pragma unroll
    for (int j = 0; j < 2; ++j) {
      const int M = 2 * Mw + j;
      aqp[j] = *(const s16x8*)(qb_b + (size_t)(m0 + M * 16 + l15) * 32 + quad * 8);
      l4p[j] = *(const float4*)(L_b + m0 + M * 16 + quad * 4);
    }
  };
  auto loadV = [&](s16x8* va, int c2, int q) {
    const int m0 = c2 * 128 + q * 32;
#pragma unroll
    for (int ci = 0; ci < 4; ++ci)
      va[ci] = *(const s16x8*)(vb_b + (size_t)(cbase + ci * 16 + l15) * 4096 + m0 + quad * 8);
  };
  // one produce tile: QK MFMA (Lneg as C-in) -> exp2 -> pack -> ds_write b64.
  auto produce_tile = [&](int buf, int j, int i) {
    char* Pw = (char*)&PT[buf][0];
    const int M = 2 * Mw + j;
    const int T = Tb + i;
    f32x4 cin; cin.x = l4p[j].x; cin.y = l4p[j].y; cin.z = l4p[j].z; cin.w = l4p[j].w;
    f32x4 s = MFMA16(aqp[j], kf[i], cin);            // S' + Lneg  (<= ~0)
    uint2 u;
    u.x = pack_bf16(fexp2(s.x), fexp2(s.y));
    u.y = pack_bf16(fexp2(s.z), fexp2(s.w));
    const int row = T * 16 + l15;
    const int gran = (2 * M + (quad >> 1)) ^ swz;    // 0..15 ^ 0..7 (bijective)
    *(uint2*)(Pw + row * 256 + gran * 16 + (quad & 1) * 8) = u;
  };
  // read 4 B-frags: quarter q (32 m), n-tiles ntb4..ntb4+3
  auto rdP4 = [&](s16x8* d, int buf, int q, int ntb4) {
    const char* P = (const char*)&PT[buf][0];
#pragma unroll
    for (int k = 0; k < 4; ++k) {
      const int row = (ntb4 + k) * 16 + l15;
      d[k] = *(const s16x8*)(P + row * 256 + (((q * 4 + quad) ^ swz) << 4));
    }
  };

  loadQ(0);
#pragma unroll
  for (int j = 0; j < 2; ++j)
#pragma unroll
    for (int i = 0; i < 4; ++i) produce_tile(0, j, i);   // prologue: produce chunk 0
  loadQ(1);
  loadV(va0, 0, 0);
  loadV(va1, 0, 1);

  for (int c2 = 0; c2 < 32; ++c2) {
    const int buf = c2 & 1;
    chunk_barrier();   // lgkm drain + s_barrier; global prefetches stay in flight
    s16x8 pg[4], rr[4];
    rdP4(pg, buf, 0, 0);
    // --- produce chunk+1 into buf^1: register-only inputs, no dep on pg ---
    // (c2=31's produce reuses aqp(31) and writes a never-read buffer: safe.)
#pragma unroll
    for (int j = 0; j < 2; ++j)
#pragma unroll
      for (int i = 0; i < 4; ++i) produce_tile(buf ^ 1, j, i);
    if (c2 < 30) loadQ(c2 + 2);
    // --- quarter 0 (va0) ---
    __builtin_amdgcn_s_setprio(1);
    rdP4(rr, buf, 0, 4);
#pragma unroll
    for (int k = 0; k < 4; ++k)
#pragma unroll
      for (int ci = 0; ci < 4; ++ci) acc[ci][k] = MFMA16(va0[ci], pg[k], acc[ci][k]);
    rdP4(pg, buf, 1, 0);
#pragma unroll
    for (int k = 0; k < 4; ++k)
#pragma unroll
      for (int ci = 0; ci < 4; ++ci) acc[ci][4 + k] = MFMA16(va0[ci], rr[k], acc[ci][4 + k]);
    __builtin_amdgcn_s_setprio(0);
    loadV(va0, c2, 2);
    // --- quarter 1 (va1) ---
    __builtin_amdgcn_s_setprio(1);
    rdP4(rr, buf, 1, 4);
#pragma unroll
    for (int k = 0; k < 4; ++k)
#pragma unroll
      for (int ci = 0; ci < 4; ++ci) acc[ci][k] = MFMA16(va1[ci], pg[k], acc[ci][k]);
    rdP4(pg, buf, 2, 0);
#pragma unroll
    for (int k = 0; k < 4; ++k)
#pragma unroll
      for (int ci = 0; ci < 4; ++ci) acc[ci][4 + k] = MFMA16(va1[ci], rr[k], acc[ci][4 + k]);
    __builtin_amdgcn_s_setprio(0);
    loadV(va1, c2, 3);
    // --- quarter 2 (va0) ---
    __builtin_amdgcn_s_setprio(1);
    rdP4(rr, buf, 2, 4);
#pragma unroll
    for (int k = 0; k < 4; ++k)
#pragma unroll
      for (int ci = 0; ci < 4; ++ci) acc[ci][k] = MFMA16(va0[ci], pg[k], acc[ci][k]);
    rdP4(pg, buf, 3, 0);
#pragma unroll
    for (int k = 0; k < 4; ++k)
#pragma unroll
      for (int ci = 0; ci < 4; ++ci) acc[ci][4 + k] = MFMA16(va0[ci], rr[k], acc[ci][4 + k]);
    __builtin_amdgcn_s_setprio(0);
    if (c2 < 31) loadV(va0, c2 + 1, 0);
    // --- quarter 3 (va1) ---
    __builtin_amdgcn_s_setprio(1);
    rdP4(rr, buf, 3, 4);
#pragma unroll
    for (int k = 0; k < 4; ++k)
#pragma unroll
      for (int ci = 0; ci < 4; ++ci) acc[ci][k] = MFMA16(va1[ci], pg[k], acc[ci][k]);
#pragma unroll
    for (int k = 0; k < 4; ++k)
#pragma unroll
      for (int ci = 0; ci < 4; ++ci) acc[ci][4 + k] = MFMA16(va1[ci], rr[k], acc[ci][4 + k]);
    __builtin_amdgcn_s_setprio(0);
    if (c2 < 31) loadV(va1, c2 + 1, 1);
  }

  float* out_b = out + (size_t)b * 512 * 4096;
#pragma unroll
  for (int ci = 0; ci < 4; ++ci)
#pragma unroll
    for (int nt = 0; nt < 8; ++nt) {
      const int n = nbase + nt * 16 + l15;
      const int c0 = cbase + ci * 16 + quad * 4;
#pragma unroll
      for (int r = 0; r < 4; ++r) out_b[(size_t)(c0 + r) * 4096 + n] = acc[ci][nt][r];
    }
}

// ---------------- launch ----------------
extern "C" void kernel_launch(void* const* d_in, const int* in_sizes, int n_in,
                              void* d_out, int out_size, void* d_ws, size_t ws_size,
                              hipStream_t stream) {
  const float* x  = (const float*)d_in[0];   // [8,512,64,64]
  const float* Wq = (const float*)d_in[1];   // [32,512]
  const float* Wk = (const float*)d_in[2];   // [32,512]
  const float* Wv = (const float*)d_in[3];   // [512,512]
  float* out = (float*)d_out;                // [8,512,64,64]

  char* ws = (char*)d_ws;
  ushort* vb  = (ushort*)(ws + 0);           // 33,554,432 B
  ushort* qb  = (ushort*)(ws + 33554432);    //  2,097,152 B
  ushort* kb  = (ushort*)(ws + 35651584);    //  2,097,152 B
  ushort* Wvb = (ushort*)(ws + 37748736);    //    524,288 B
  ushort* Wqb = (ushort*)(ws + 38273024);    //     32,768 B
  ushort* Wkb = (ushort*)(ws + 38305792);    //     32,768 B
  float*  Lrs = (float*)(ws + 38338560);     //    131,072 B  (total 38,469,632)

  hipLaunchKernelGGL(k_cvt_w, dim3(1152), dim3(256), 0, stream, Wq, Wk, Wv, Wqb, Wkb, Wvb);
  hipLaunchKernelGGL(k_proj, dim3(64, 8), dim3(256), 0, stream, x, Wqb, Wkb, Wvb, qb, kb, vb);
  hipLaunchKernelGGL(k_pass1, dim3(64, 8), dim3(256), 0, stream, qb, kb, Lrs);
  hipLaunchKernelGGL(k_pass2, dim3(256), dim3(512), 0, stream, qb, kb, vb, Lrs, out);
}